// Round 15
// baseline (1023.342 us; speedup 1.0000x reference)
//
#include <hip/hip_runtime.h>
#include <hip/hip_bf16.h>

#define B_ 2
#define T_ 2048
#define C_ 4096
#define H_ 32
#define D_ 128

typedef __bf16 bf16x8 __attribute__((ext_vector_type(8)));
typedef float f32x4 __attribute__((ext_vector_type(4)));

__device__ __forceinline__ void gload_lds16(const void* g, void* l) {
  __builtin_amdgcn_global_load_lds(
      (const __attribute__((address_space(1))) void*)g,
      (__attribute__((address_space(3))) void*)l, 16, 0, 0);
}

__device__ __forceinline__ ushort f2bf(float f) {
  union { float f; uint u; } x; x.f = f;
  uint r = x.u + 0x7FFFu + ((x.u >> 16) & 1u);   // round-to-nearest-even
  return (ushort)(r >> 16);
}

// ---------------------------------------------------------------------------
// fp32 -> bf16 elementwise convert (8 elements/thread)
// ---------------------------------------------------------------------------
__global__ __launch_bounds__(256) void cvt_f32_bf16(
    const float* __restrict__ in, ushort* __restrict__ out)
{
  long i = ((long)blockIdx.x * 256 + threadIdx.x) * 8;
  float4 a = *(const float4*)&in[i];
  float4 b = *(const float4*)&in[i + 4];
  union { ushort u[8]; uint4 v; } g;
  g.u[0] = f2bf(a.x); g.u[1] = f2bf(a.y); g.u[2] = f2bf(a.z); g.u[3] = f2bf(a.w);
  g.u[4] = f2bf(b.x); g.u[5] = f2bf(b.y); g.u[6] = f2bf(b.z); g.u[7] = f2bf(b.w);
  *(uint4*)&out[i] = g.v;
}

// ---------------------------------------------------------------------------
// Fused transpose + fp32->bf16 convert: out[c][r] = bf16(in[r][c]).
// ---------------------------------------------------------------------------
__global__ __launch_bounds__(256) void transpose_f32_bf16(
    const float* __restrict__ in, ushort* __restrict__ out, int ldi, int ldo)
{
  __shared__ __align__(16) ushort tile[64][72];
  const float* ip = in + (long)blockIdx.y * 64 * ldi + (long)blockIdx.x * 64;
  ushort* op = out + (long)blockIdx.x * 64 * ldo + (long)blockIdx.y * 64;
  const int t = threadIdx.x;
  const int row = t >> 2, c0 = (t & 3) * 16;
#pragma unroll
  for (int v = 0; v < 4; ++v) {
    float4 f = *(const float4*)&ip[(long)row * ldi + c0 + v * 4];
    ushort4 w;
    w.x = f2bf(f.x); w.y = f2bf(f.y); w.z = f2bf(f.z); w.w = f2bf(f.w);
    *(ushort4*)&tile[row][c0 + v * 4] = w;
  }
  __syncthreads();
#pragma unroll
  for (int i = 0; i < 2; ++i) {
    int t2 = i * 256 + t;
    int orow = t2 >> 3, ch = t2 & 7;
    union { ushort u[8]; uint4 v; } g;
#pragma unroll
    for (int e = 0; e < 8; ++e) g.u[e] = tile[ch * 8 + e][orow];
    *(uint4*)&op[(long)orow * ldo + ch * 8] = g.v;
  }
}

// ---------------------------------------------------------------------------
// bf16 transpose with z-striding (for V -> Vt[b,h,d,t]).
// ---------------------------------------------------------------------------
__global__ __launch_bounds__(256) void transpose_bf16(
    const ushort* __restrict__ in, ushort* __restrict__ out,
    int ldi, int ldo, long zi1, long zi2, long zo1, long zo2)
{
  __shared__ __align__(16) ushort tile[64][72];
  const int z = blockIdx.z;
  const long z1 = z & 31, z2 = z >> 5;
  const ushort* ip = in + z1 * zi1 + z2 * zi2 +
                     (long)blockIdx.y * 64 * ldi + (long)blockIdx.x * 64;
  ushort* op = out + z1 * zo1 + z2 * zo2 +
               (long)blockIdx.x * 64 * ldo + (long)blockIdx.y * 64;
  const int t = threadIdx.x;
#pragma unroll
  for (int i = 0; i < 2; ++i) {
    int t2 = i * 256 + t;
    int row = t2 >> 3, ch = t2 & 7;
    *(uint4*)&tile[row][ch * 8] = *(const uint4*)&ip[(long)row * ldi + ch * 8];
  }
  __syncthreads();
#pragma unroll
  for (int i = 0; i < 2; ++i) {
    int t2 = i * 256 + t;
    int orow = t2 >> 3, ch = t2 & 7;
    union { ushort u[8]; uint4 v; } g;
#pragma unroll
    for (int e = 0; e < 8; ++e) g.u[e] = tile[ch * 8 + e][orow];
    *(uint4*)&op[(long)orow * ldo + ch * 8] = g.v;
  }
}

// ===========================================================================
// GEMM 256x256 tile, BK=64, 128 KiB LDS, 8 waves, 4-phase Gray schedule,
// deep prefetch (t+2), B-frags persistent in regs, counted vmcnt(8),
// XOR-chunk LDS swizzle via pre-swizzled global source, XCD-bijective
// block swizzle. Best-known single-GEMM config (R7/R8/R13: 176 us, grid 256).
// ===========================================================================
#define STAGE_A64(h, tt) do {                                                  \
    __hip_bfloat16* dst_ = AS + ((((tt) & 1) * 2 + (h)) * 8192) + w * 512;     \
    const __hip_bfloat16* src_ = Asrc + (size_t)((h) * 128) * K + (size_t)(tt) * 64; \
    gload_lds16(src_, dst_);                                                   \
    gload_lds16(src_ + (size_t)64 * K, dst_ + 4096);                           \
  } while (0)

#define STAGE_B64(h, tt) do {                                                  \
    __hip_bfloat16* dst_ = BS + ((((tt) & 1) * 2 + (h)) * 8192) + w * 512;     \
    const __hip_bfloat16* src_ = Bsrc + (size_t)((h) * 128) * K + (size_t)(tt) * 64; \
    gload_lds16(src_, dst_);                                                   \
    gload_lds16(src_ + (size_t)64 * K, dst_ + 4096);                           \
  } while (0)

#define MFMA16(pM, pN, AF, BF)                                                 \
  _Pragma("unroll")                                                            \
  for (int mf = 0; mf < 4; ++mf)                                               \
    _Pragma("unroll")                                                          \
    for (int nf = 0; nf < 2; ++nf)                                             \
      _Pragma("unroll")                                                        \
      for (int ks = 0; ks < 2; ++ks)                                           \
        acc[pM][pN][mf][nf] = __builtin_amdgcn_mfma_f32_16x16x32_bf16(         \
            AF[mf][ks], BF[nf][ks], acc[pM][pN][mf][nf], 0, 0, 0);

template <typename OutT>
__global__ __launch_bounds__(512, 2) void gemm256(
    const __hip_bfloat16* __restrict__ A,
    const __hip_bfloat16* __restrict__ Bt,
    OutT* __restrict__ C,
    int M, int N, int K, int rope_mode)
{
  extern __shared__ __hip_bfloat16 smem[];
  __hip_bfloat16* AS = smem;            // 2 buf x 2 half x 8192 elem (64 KiB)
  __hip_bfloat16* BS = smem + 32768;    // same (64 KiB)

  const int tid = threadIdx.x, lane = tid & 63, w = tid >> 6;
  const int wm = w >> 2, wn = w & 3;          // 2M x 4N wave grid
  const int fr = lane & 15, quad = lane >> 4;

  // XCD-bijective block swizzle (nwg=256, 256%8==0)
  const int bid = blockIdx.x;
  const int s = (bid & 7) * 32 + (bid >> 3);
  const int m0 = (s >> 4) * 256, n0 = (s & 15) * 256;

  // staging source: thread covers row (tid>>3), 16B chunk pre-swizzled
  const int srow = tid >> 3;                       // 0..63
  const int schunk = ((tid & 7) ^ (srow & 7)) * 8;
  const __hip_bfloat16* Asrc = A + (size_t)(m0 + srow) * K + schunk;
  const __hip_bfloat16* Bsrc = Bt + (size_t)(n0 + srow) * K + schunk;

  f32x4 acc[2][2][4][2] = {};

  // ---- prologue: tiles 0 and 1 fully staged ----
  STAGE_A64(0, 0); STAGE_B64(0, 0); STAGE_A64(1, 0); STAGE_B64(1, 0);
  STAGE_A64(0, 1); STAGE_B64(0, 1); STAGE_A64(1, 1); STAGE_B64(1, 1);
  asm volatile("s_waitcnt vmcnt(8)" ::: "memory");   // tile0 landed
  asm volatile("s_barrier" ::: "memory");

  const int NT = K >> 6;
  for (int t = 0; t < NT; ++t) {
    const __hip_bfloat16* As0 = AS + (t & 1) * 16384;
    const __hip_bfloat16* Bs0 = BS + (t & 1) * 16384;
    bf16x8 af[4][2], b0[2][2], b1[2][2];

    // ---------- phase 0: read A-h0 + B-h0; MFMA (0,0) ----------
#pragma unroll
    for (int mf = 0; mf < 4; ++mf) {
      const int row = wm * 64 + mf * 16 + fr;
#pragma unroll
      for (int ks = 0; ks < 2; ++ks)
        af[mf][ks] = *(const bf16x8*)
            &As0[row * 64 + (((ks * 4 + quad) ^ (fr & 7)) << 3)];
    }
#pragma unroll
    for (int nf = 0; nf < 2; ++nf) {
      const int row = wn * 32 + nf * 16 + fr;
#pragma unroll
      for (int ks = 0; ks < 2; ++ks)
        b0[nf][ks] = *(const bf16x8*)
            &Bs0[row * 64 + (((ks * 4 + quad) ^ (fr & 7)) << 3)];
    }
    asm volatile("s_barrier" ::: "memory");
    asm volatile("s_waitcnt lgkmcnt(0)" ::: "memory");
    __builtin_amdgcn_s_setprio(1);
    MFMA16(0, 0, af, b0)
    __builtin_amdgcn_s_setprio(0);
    asm volatile("s_barrier" ::: "memory");

    // ---------- phase 1: read B-h1; stage B0,A0 (t+2); MFMA (0,1) ----------
#pragma unroll
    for (int nf = 0; nf < 2; ++nf) {
      const int row = wn * 32 + nf * 16 + fr;
#pragma unroll
      for (int ks = 0; ks < 2; ++ks)
        b1[nf][ks] = *(const bf16x8*)
            &Bs0[8192 + row * 64 + (((ks * 4 + quad) ^ (fr & 7)) << 3)];
    }
    if (t + 2 < NT) { STAGE_B64(0, t + 2); STAGE_A64(0, t + 2); }
    asm volatile("s_barrier" ::: "memory");
    asm volatile("s_waitcnt lgkmcnt(0)" ::: "memory");
    __builtin_amdgcn_s_setprio(1);
    MFMA16(0, 1, af, b1)
    __builtin_amdgcn_s_setprio(0);
    asm volatile("s_barrier" ::: "memory");

    // ---------- phase 2: read A-h1; stage B1(t+2); MFMA (1,1) ----------
#pragma unroll
    for (int mf = 0; mf < 4; ++mf) {
      const int row = wm * 64 + mf * 16 + fr;
#pragma unroll
      for (int ks = 0; ks < 2; ++ks)
        af[mf][ks] = *(const bf16x8*)
            &As0[8192 + row * 64 + (((ks * 4 + quad) ^ (fr & 7)) << 3)];
    }
    if (t + 2 < NT) STAGE_B64(1, t + 2);
    asm volatile("s_barrier" ::: "memory");
    asm volatile("s_waitcnt lgkmcnt(0)" ::: "memory");
    __builtin_amdgcn_s_setprio(1);
    MFMA16(1, 1, af, b1)
    __builtin_amdgcn_s_setprio(0);
    asm volatile("s_barrier" ::: "memory");

    // ---------- phase 3: stage A1(t+2); counted vmcnt; MFMA (1,0) ----------
    if (t + 2 < NT) STAGE_A64(1, t + 2);
    if (t < NT - 2) asm volatile("s_waitcnt vmcnt(8)" ::: "memory");
    else            asm volatile("s_waitcnt vmcnt(0)" ::: "memory");
    asm volatile("s_barrier" ::: "memory");
    __builtin_amdgcn_s_setprio(1);
    MFMA16(1, 0, af, b0)
    __builtin_amdgcn_s_setprio(0);
    asm volatile("s_barrier" ::: "memory");
  }

  // ---- epilogue (C/D: row = quad*4+reg rel. M-frag, col = fr rel. N-frag) ----
  const float gscale = (rope_mode == 1) ? 0.08838834764831845f : 1.0f;
  float freqv[2] = {0.f, 0.f};
  if (rope_mode) {
#pragma unroll
    for (int nf = 0; nf < 2; ++nf)
      freqv[nf] = exp2f((float)((wn & 1) * 32 + nf * 16 + fr) *
                        -0.20762050593046012f);
  }
#pragma unroll
  for (int pM = 0; pM < 2; ++pM)
#pragma unroll
    for (int mf = 0; mf < 4; ++mf)
#pragma unroll
      for (int r = 0; r < 4; ++r) {
        const int grow = m0 + pM * 128 + wm * 64 + mf * 16 + quad * 4 + r;
        float fct[2] = {1.f, 1.f};
        if (rope_mode) {
          const int tt = grow & (T_ - 1);
#pragma unroll
          for (int nf = 0; nf < 2; ++nf) {
            float sn, cs;
            sincosf((float)tt * freqv[nf], &sn, &cs);
            fct[nf] = (cs + sn) * gscale;
          }
        }
#pragma unroll
        for (int pN = 0; pN < 2; ++pN)
#pragma unroll
          for (int nf = 0; nf < 2; ++nf) {
            const int col = n0 + pN * 128 + wn * 32 + nf * 16 + fr;
            float v = acc[pM][pN][mf][nf][r] * fct[nf];
            if constexpr (sizeof(OutT) == 4)
              C[(size_t)grow * N + col] = v;
            else
              C[(size_t)grow * N + col] = __float2bfloat16(v);
          }
      }
}

// ---------------------------------------------------------------------------
// Flash attention (causal). Best-known config (R7/R8/R13: 189-191 us):
// grid (8,64) two-pass balanced (qt=bx then 15-bx, 17 K-tile units/block);
// R2 dataflow (V staged into shared Ks after QK; DMA lands during softmax,
// which is VALU-only); halved per-wave Ps (48 KiB LDS); launch_bounds(256,2)
// (VGPR 128, no spill -- NEVER cap below 128: R4's (256,3) forced VGPR 84
// and spilled the accumulators, 2x regression).
// Grid notes: (12,64) 3-blocks/CU REGRESSED (R12); 1024 single-tile blocks
// REGRESSED (R5); K/V split-buffer deep pipeline REGRESSED (R6).
// ---------------------------------------------------------------------------
__global__ __launch_bounds__(256, 2) void flash_attn(
    const __hip_bfloat16* __restrict__ Q,
    const __hip_bfloat16* __restrict__ K,
    const __hip_bfloat16* __restrict__ Vt,
    __hip_bfloat16* __restrict__ O)
{
  __shared__ __align__(16) __hip_bfloat16 Ks[128 * 128];
  __shared__ __align__(16) __hip_bfloat16 Ps[4][32 * 64];
  const int tid = threadIdx.x, lane = tid & 63, wid = tid >> 6;
  const int bx = blockIdx.x, bh = blockIdx.y;
  const int b = bh >> 5, h = bh & 31;
  const int fr = lane & 15;
  const int quad = lane >> 4;
  const __hip_bfloat16* Kbase = K + (size_t)(b * T_) * C_ + h * D_;
  const __hip_bfloat16* Vbase = Vt + (size_t)bh * D_ * T_;

  const int strow = wid * 32 + quad;  // +4 per j

  for (int pass = 0; pass < 2; ++pass) {
    const int qt = pass ? (15 - bx) : bx;
    const int q0 = qt * 128;
    const __hip_bfloat16* Qbase = Q + (size_t)(b * T_ + q0) * C_ + h * D_;

    // ---- stage Q tile (source-swizzled), pull fragments ----
#pragma unroll
    for (int j = 0; j < 8; ++j) {
      const int swz = quad + (j & 1) * 4;
      gload_lds16(Qbase + (size_t)(strow + j * 4) * C_ + ((fr ^ swz) * 8),
                  &Ks[(wid * 8 + j) * 512]);
    }
    __syncthreads();
    bf16x8 qf[2][4];
#pragma unroll
    for (int mi = 0; mi < 2; ++mi)
#pragma unroll
      for (int ks = 0; ks < 4; ++ks)
        qf[mi][ks] = *(const bf16x8*)&Ks[(wid * 32 + mi * 16 + fr) * 128 +
                                         (((ks * 4 + quad) ^ (fr & 7)) << 3)];
    __syncthreads();

    float m_i[2][4], l_i[2][4];
#pragma unroll
    for (int mi = 0; mi < 2; ++mi)
#pragma unroll
      for (int r = 0; r < 4; ++r) { m_i[mi][r] = -1e30f; l_i[mi][r] = 0.f; }
    f32x4 oa[2][8] = {};

    for (int kt = 0; kt <= qt; ++kt) {
#pragma unroll
      for (int j = 0; j < 8; ++j) {
        const int swz = quad + (j & 1) * 4;
        gload_lds16(
            Kbase + (size_t)(kt * 128 + strow + j * 4) * C_ + ((fr ^ swz) * 8),
            &Ks[(wid * 8 + j) * 512]);
      }
      __syncthreads();

      f32x4 s[2][8] = {};
#pragma unroll
      for (int ks = 0; ks < 4; ++ks) {
        bf16x8 kf[8];
#pragma unroll
        for (int ni = 0; ni < 8; ++ni)
          kf[ni] = *(const bf16x8*)&Ks[(ni * 16 + fr) * 128 +
                                       (((ks * 4 + quad) ^ (fr & 7)) << 3)];
        __builtin_amdgcn_s_setprio(1);
#pragma unroll
        for (int mi = 0; mi < 2; ++mi)
#pragma unroll
          for (int ni = 0; ni < 8; ++ni)
            s[mi][ni] = __builtin_amdgcn_mfma_f32_16x16x32_bf16(
                qf[mi][ks], kf[ni], s[mi][ni], 0, 0, 0);
        __builtin_amdgcn_s_setprio(0);
      }
      __syncthreads();  // K tile consumed

      // stage Vt tile into the same buffer (async; lands during softmax)
#pragma unroll
      for (int j = 0; j < 8; ++j) {
        const int swz = quad + (j & 1) * 4;
        gload_lds16(
            Vbase + (size_t)(strow + j * 4) * T_ + kt * 128 + ((fr ^ swz) * 8),
            &Ks[(wid * 8 + j) * 512]);
      }

      if (kt == qt) {
#pragma unroll
        for (int mi = 0; mi < 2; ++mi)
#pragma unroll
          for (int ni = 0; ni < 8; ++ni)
#pragma unroll
            for (int r = 0; r < 4; ++r) {
              int rl = wid * 32 + mi * 16 + quad * 4 + r;
              int cl = ni * 16 + fr;
              if (cl > rl) s[mi][ni][r] = -1e30f;
            }
      }

      // ---- softmax (single path, always rescale) ----
#pragma unroll
      for (int mi = 0; mi < 2; ++mi)
#pragma unroll
        for (int r = 0; r < 4; ++r) {
          float mx = -1e30f;
#pragma unroll
          for (int ni = 0; ni < 8; ++ni) mx = fmaxf(mx, s[mi][ni][r]);
          mx = fmaxf(mx, __shfl_xor(mx, 1, 16));
          mx = fmaxf(mx, __shfl_xor(mx, 2, 16));
          mx = fmaxf(mx, __shfl_xor(mx, 4, 16));
          mx = fmaxf(mx, __shfl_xor(mx, 8, 16));
          float mnew = fmaxf(m_i[mi][r], mx);
          float alpha = __expf(m_i[mi][r] - mnew);
          float rs = 0.f;
#pragma unroll
          for (int ni = 0; ni < 8; ++ni) {
            float p = __expf(s[mi][ni][r] - mnew);
            s[mi][ni][r] = p;
            rs += p;
          }
          rs += __shfl_xor(rs, 1, 16);
          rs += __shfl_xor(rs, 2, 16);
          rs += __shfl_xor(rs, 4, 16);
          rs += __shfl_xor(rs, 8, 16);
          m_i[mi][r] = mnew;
          l_i[mi][r] = l_i[mi][r] * alpha + rs;
#pragma unroll
          for (int ni = 0; ni < 8; ++ni) oa[mi][ni][r] *= alpha;
        }

      // ---- P round-trip in two 64-col halves + PV ----
#pragma unroll
      for (int hh = 0; hh < 2; ++hh) {
        // write P half hh (cols hh*64 .. hh*64+63) into per-wave Ps
#pragma unroll
        for (int mi = 0; mi < 2; ++mi)
#pragma unroll
          for (int l = 0; l < 4; ++l) {
            const int sw = (l ^ quad) & 3;
#pragma unroll
            for (int r = 0; r < 4; ++r)
              Ps[wid][(mi * 16 + quad * 4 + r) * 64 + sw * 16 + fr] =
                  __float2bfloat16(s[mi][hh * 4 + l][r]);
          }
        if (hh == 0) __syncthreads();  // Vt landed (vmcnt drained)
        // PV for ks = hh*2, hh*2+1 (wave-ordered LDS: no barrier for hh=1)
#pragma unroll
        for (int kl = 0; kl < 2; ++kl) {
          const int ks = hh * 2 + kl;
          bf16x8 pf[2], vf[8];
#pragma unroll
          for (int mi = 0; mi < 2; ++mi) {
            const int rowl = mi * 16 + fr;
            const int sw = ((kl * 2 + (quad >> 1)) ^ ((fr >> 2) & 3)) & 3;
            pf[mi] = *(const bf16x8*)
                &Ps[wid][rowl * 64 + sw * 16 + (quad & 1) * 8];
          }
#pragma unroll
          for (int ni = 0; ni < 8; ++ni)
            vf[ni] = *(const bf16x8*)&Ks[(ni * 16 + fr) * 128 +
                                         (((ks * 4 + quad) ^ (fr & 7)) << 3)];
          __builtin_amdgcn_s_setprio(1);
#pragma unroll
          for (int mi = 0; mi < 2; ++mi)
#pragma unroll
            for (int ni = 0; ni < 8; ++ni)
              oa[mi][ni] = __builtin_amdgcn_mfma_f32_16x16x32_bf16(
                  pf[mi], vf[ni], oa[mi][ni], 0, 0, 0);
          __builtin_amdgcn_s_setprio(0);
        }
      }
      __syncthreads();  // Vt/Ps consumed
    }

    // ---- epilogue: O / l ----
#pragma unroll
    for (int mi = 0; mi < 2; ++mi)
#pragma unroll
      for (int r = 0; r < 4; ++r) {
        float inv = 1.f / l_i[mi][r];
        int grow = b * T_ + q0 + wid * 32 + mi * 16 + quad * 4 + r;
#pragma unroll
        for (int ni = 0; ni < 8; ++ni)
          O[(size_t)grow * C_ + h * D_ + ni * 16 + fr] =
              __float2bfloat16(oa[mi][ni][r] * inv);
      }
  }
}

// ---------------------------------------------------------------------------
extern "C" void kernel_launch(void* const* d_in, const int* in_sizes, int n_in,
                              void* d_out, int out_size, void* d_ws, size_t ws_size,
                              hipStream_t stream) {
  const float* X  = (const float*)d_in[0];
  const float* Wq = (const float*)d_in[1];
  const float* Wk = (const float*)d_in[2];
  const float* Wv = (const float*)d_in[3];
  const float* Wo = (const float*)d_in[4];
  float* out = (float*)d_out;

  char* ws = (char*)d_ws;
  const size_t SZ = (size_t)4096 * 4096 * 2;  // 32 MiB per bf16 slab
  __hip_bfloat16* Xb  = (__hip_bfloat16*)(ws);
  __hip_bfloat16* Wt  = (__hip_bfloat16*)(ws + SZ);
  __hip_bfloat16* Qb  = (__hip_bfloat16*)(ws + 2 * SZ);
  __hip_bfloat16* Kb  = (__hip_bfloat16*)(ws + 3 * SZ);
  __hip_bfloat16* Vb  = (__hip_bfloat16*)(ws + 4 * SZ);
  __hip_bfloat16* Vtb = Xb;   // Xb dead after QKV GEMMs
  __hip_bfloat16* Ob  = Vb;   // V dead after Vt transpose

  const dim3 blk(256);
  const dim3 gT(64, 64, 1);

  // 128 KiB dynamic LDS for the 256^2 GEMM
  hipFuncSetAttribute(reinterpret_cast<const void*>(&gemm256<__hip_bfloat16>),
                      hipFuncAttributeMaxDynamicSharedMemorySize, 131072);
  hipFuncSetAttribute(reinterpret_cast<const void*>(&gemm256<float>),
                      hipFuncAttributeMaxDynamicSharedMemorySize, 131072);

  // X -> bf16
  cvt_f32_bf16<<<8192, blk, 0, stream>>>(X, (ushort*)Xb);

  // Q = rope(X @ Wq) / sqrt(D) ; K = rope(X @ Wk) ; V = X @ Wv
  transpose_f32_bf16<<<gT, blk, 0, stream>>>(Wq, (ushort*)Wt, 4096, 4096);
  gemm256<__hip_bfloat16><<<dim3(256), dim3(512), 131072, stream>>>(
      Xb, Wt, Qb, 4096, 4096, 4096, 1);
  transpose_f32_bf16<<<gT, blk, 0, stream>>>(Wk, (ushort*)Wt, 4096, 4096);
  gemm256<__hip_bfloat16><<<dim3(256), dim3(512), 131072, stream>>>(
      Xb, Wt, Kb, 4096, 4096, 4096, 2);
  transpose_f32_bf16<<<gT, blk, 0, stream>>>(Wv, (ushort*)Wt, 4096, 4096);
  gemm256<__hip_bfloat16><<<dim3(256), dim3(512), 131072, stream>>>(
      Xb, Wt, Vb, 4096, 4096, 4096, 0);

  // Vt[b,h,d,t] = V[b,t,h*128+d]
  transpose_bf16<<<dim3(2, 32, 64), blk, 0, stream>>>(
      (const ushort*)Vb, (ushort*)Vtb, 4096, 2048,
      /*zi1 h*/ 128, /*zi2 b*/ 8388608, /*zo1 h*/ 262144, /*zo2 b*/ 8388608);

  // attention (balanced two-pass causal schedule)
  flash_attn<<<dim3(8, 64), blk, 0, stream>>>(Qb, Kb, Vtb, Ob);

  // out = O @ Wo  (fp32 output)
  transpose_f32_bf16<<<gT, blk, 0, stream>>>(Wo, (ushort*)Wt, 4096, 4096);
  gemm256<float><<<dim3(256), dim3(512), 131072, stream>>>(
      Ob, Wt, out, 4096, 4096, 4096, 0);
}

// Round 16
// 1013.497 us; speedup vs baseline: 1.0097x; 1.0097x over previous
//
#include <hip/hip_runtime.h>
#include <hip/hip_bf16.h>

#define B_ 2
#define T_ 2048
#define C_ 4096
#define H_ 32
#define D_ 128

typedef __bf16 bf16x8 __attribute__((ext_vector_type(8)));
typedef float f32x4 __attribute__((ext_vector_type(4)));

__device__ __forceinline__ void gload_lds16(const void* g, void* l) {
  __builtin_amdgcn_global_load_lds(
      (const __attribute__((address_space(1))) void*)g,
      (__attribute__((address_space(3))) void*)l, 16, 0, 0);
}

__device__ __forceinline__ ushort f2bf(float f) {
  union { float f; uint u; } x; x.f = f;
  uint r = x.u + 0x7FFFu + ((x.u >> 16) & 1u);   // round-to-nearest-even
  return (ushort)(r >> 16);
}

// ---------------------------------------------------------------------------
// fp32 -> bf16 elementwise convert (8 elements/thread)
// ---------------------------------------------------------------------------
__global__ __launch_bounds__(256) void cvt_f32_bf16(
    const float* __restrict__ in, ushort* __restrict__ out)
{
  long i = ((long)blockIdx.x * 256 + threadIdx.x) * 8;
  float4 a = *(const float4*)&in[i];
  float4 b = *(const float4*)&in[i + 4];
  union { ushort u[8]; uint4 v; } g;
  g.u[0] = f2bf(a.x); g.u[1] = f2bf(a.y); g.u[2] = f2bf(a.z); g.u[3] = f2bf(a.w);
  g.u[4] = f2bf(b.x); g.u[5] = f2bf(b.y); g.u[6] = f2bf(b.z); g.u[7] = f2bf(b.w);
  *(uint4*)&out[i] = g.v;
}

// ---------------------------------------------------------------------------
// Fused transpose + fp32->bf16 convert: out[c][r] = bf16(in[r][c]).
// ---------------------------------------------------------------------------
__global__ __launch_bounds__(256) void transpose_f32_bf16(
    const float* __restrict__ in, ushort* __restrict__ out, int ldi, int ldo)
{
  __shared__ __align__(16) ushort tile[64][72];
  const float* ip = in + (long)blockIdx.y * 64 * ldi + (long)blockIdx.x * 64;
  ushort* op = out + (long)blockIdx.x * 64 * ldo + (long)blockIdx.y * 64;
  const int t = threadIdx.x;
  const int row = t >> 2, c0 = (t & 3) * 16;
#pragma unroll
  for (int v = 0; v < 4; ++v) {
    float4 f = *(const float4*)&ip[(long)row * ldi + c0 + v * 4];
    ushort4 w;
    w.x = f2bf(f.x); w.y = f2bf(f.y); w.z = f2bf(f.z); w.w = f2bf(f.w);
    *(ushort4*)&tile[row][c0 + v * 4] = w;
  }
  __syncthreads();
#pragma unroll
  for (int i = 0; i < 2; ++i) {
    int t2 = i * 256 + t;
    int orow = t2 >> 3, ch = t2 & 7;
    union { ushort u[8]; uint4 v; } g;
#pragma unroll
    for (int e = 0; e < 8; ++e) g.u[e] = tile[ch * 8 + e][orow];
    *(uint4*)&op[(long)orow * ldo + ch * 8] = g.v;
  }
}

// ---------------------------------------------------------------------------
// bf16 transpose with z-striding (for V -> Vt[b,h,d,t]).
// ---------------------------------------------------------------------------
__global__ __launch_bounds__(256) void transpose_bf16(
    const ushort* __restrict__ in, ushort* __restrict__ out,
    int ldi, int ldo, long zi1, long zi2, long zo1, long zo2)
{
  __shared__ __align__(16) ushort tile[64][72];
  const int z = blockIdx.z;
  const long z1 = z & 31, z2 = z >> 5;
  const ushort* ip = in + z1 * zi1 + z2 * zi2 +
                     (long)blockIdx.y * 64 * ldi + (long)blockIdx.x * 64;
  ushort* op = out + z1 * zo1 + z2 * zo2 +
               (long)blockIdx.x * 64 * ldo + (long)blockIdx.y * 64;
  const int t = threadIdx.x;
#pragma unroll
  for (int i = 0; i < 2; ++i) {
    int t2 = i * 256 + t;
    int row = t2 >> 3, ch = t2 & 7;
    *(uint4*)&tile[row][ch * 8] = *(const uint4*)&ip[(long)row * ldi + ch * 8];
  }
  __syncthreads();
#pragma unroll
  for (int i = 0; i < 2; ++i) {
    int t2 = i * 256 + t;
    int orow = t2 >> 3, ch = t2 & 7;
    union { ushort u[8]; uint4 v; } g;
#pragma unroll
    for (int e = 0; e < 8; ++e) g.u[e] = tile[ch * 8 + e][orow];
    *(uint4*)&op[(long)orow * ldo + ch * 8] = g.v;
  }
}

// ===========================================================================
// GEMM 256x256 tile, BK=64, 128 KiB LDS, 8 waves, 4-phase Gray schedule,
// deep prefetch (t+2), B-frags persistent in regs, counted vmcnt(8),
// XOR-chunk LDS swizzle via pre-swizzled global source, XCD-bijective
// block swizzle. Best-known single-GEMM config (R7/R8/R13: ~176 us, grid 256).
// Session notes: sched_barrier(0) removal = null; BK=32 = regressed
// (barrier-rate up, no overlap gain at grid=256=1 block/CU); fused-QKV
// (grid 768, 2 blocks/CU) = faster in-dispatch (428 vs 528 us, MfmaUtil 43%)
// but consistently slower end-to-end (~+100 us systemic, never localized).
// ===========================================================================
#define STAGE_A64(h, tt) do {                                                  \
    __hip_bfloat16* dst_ = AS + ((((tt) & 1) * 2 + (h)) * 8192) + w * 512;     \
    const __hip_bfloat16* src_ = Asrc + (size_t)((h) * 128) * K + (size_t)(tt) * 64; \
    gload_lds16(src_, dst_);                                                   \
    gload_lds16(src_ + (size_t)64 * K, dst_ + 4096);                           \
  } while (0)

#define STAGE_B64(h, tt) do {                                                  \
    __hip_bfloat16* dst_ = BS + ((((tt) & 1) * 2 + (h)) * 8192) + w * 512;     \
    const __hip_bfloat16* src_ = Bsrc + (size_t)((h) * 128) * K + (size_t)(tt) * 64; \
    gload_lds16(src_, dst_);                                                   \
    gload_lds16(src_ + (size_t)64 * K, dst_ + 4096);                           \
  } while (0)

#define MFMA16(pM, pN, AF, BF)                                                 \
  _Pragma("unroll")                                                            \
  for (int mf = 0; mf < 4; ++mf)                                               \
    _Pragma("unroll")                                                          \
    for (int nf = 0; nf < 2; ++nf)                                             \
      _Pragma("unroll")                                                        \
      for (int ks = 0; ks < 2; ++ks)                                           \
        acc[pM][pN][mf][nf] = __builtin_amdgcn_mfma_f32_16x16x32_bf16(         \
            AF[mf][ks], BF[nf][ks], acc[pM][pN][mf][nf], 0, 0, 0);

template <typename OutT>
__global__ __launch_bounds__(512, 2) void gemm256(
    const __hip_bfloat16* __restrict__ A,
    const __hip_bfloat16* __restrict__ Bt,
    OutT* __restrict__ C,
    int M, int N, int K, int rope_mode)
{
  extern __shared__ __hip_bfloat16 smem[];
  __hip_bfloat16* AS = smem;            // 2 buf x 2 half x 8192 elem (64 KiB)
  __hip_bfloat16* BS = smem + 32768;    // same (64 KiB)

  const int tid = threadIdx.x, lane = tid & 63, w = tid >> 6;
  const int wm = w >> 2, wn = w & 3;          // 2M x 4N wave grid
  const int fr = lane & 15, quad = lane >> 4;

  // XCD-bijective block swizzle (nwg=256, 256%8==0)
  const int bid = blockIdx.x;
  const int s = (bid & 7) * 32 + (bid >> 3);
  const int m0 = (s >> 4) * 256, n0 = (s & 15) * 256;

  // staging source: thread covers row (tid>>3), 16B chunk pre-swizzled
  const int srow = tid >> 3;                       // 0..63
  const int schunk = ((tid & 7) ^ (srow & 7)) * 8;
  const __hip_bfloat16* Asrc = A + (size_t)(m0 + srow) * K + schunk;
  const __hip_bfloat16* Bsrc = Bt + (size_t)(n0 + srow) * K + schunk;

  f32x4 acc[2][2][4][2] = {};

  // ---- prologue: tiles 0 and 1 fully staged ----
  STAGE_A64(0, 0); STAGE_B64(0, 0); STAGE_A64(1, 0); STAGE_B64(1, 0);
  STAGE_A64(0, 1); STAGE_B64(0, 1); STAGE_A64(1, 1); STAGE_B64(1, 1);
  asm volatile("s_waitcnt vmcnt(8)" ::: "memory");   // tile0 landed
  asm volatile("s_barrier" ::: "memory");

  const int NT = K >> 6;
  for (int t = 0; t < NT; ++t) {
    const __hip_bfloat16* As0 = AS + (t & 1) * 16384;
    const __hip_bfloat16* Bs0 = BS + (t & 1) * 16384;
    bf16x8 af[4][2], b0[2][2], b1[2][2];

    // ---------- phase 0: read A-h0 + B-h0; MFMA (0,0) ----------
#pragma unroll
    for (int mf = 0; mf < 4; ++mf) {
      const int row = wm * 64 + mf * 16 + fr;
#pragma unroll
      for (int ks = 0; ks < 2; ++ks)
        af[mf][ks] = *(const bf16x8*)
            &As0[row * 64 + (((ks * 4 + quad) ^ (fr & 7)) << 3)];
    }
#pragma unroll
    for (int nf = 0; nf < 2; ++nf) {
      const int row = wn * 32 + nf * 16 + fr;
#pragma unroll
      for (int ks = 0; ks < 2; ++ks)
        b0[nf][ks] = *(const bf16x8*)
            &Bs0[row * 64 + (((ks * 4 + quad) ^ (fr & 7)) << 3)];
    }
    asm volatile("s_barrier" ::: "memory");
    asm volatile("s_waitcnt lgkmcnt(0)" ::: "memory");
    __builtin_amdgcn_s_setprio(1);
    MFMA16(0, 0, af, b0)
    __builtin_amdgcn_s_setprio(0);
    asm volatile("s_barrier" ::: "memory");

    // ---------- phase 1: read B-h1; stage B0,A0 (t+2); MFMA (0,1) ----------
#pragma unroll
    for (int nf = 0; nf < 2; ++nf) {
      const int row = wn * 32 + nf * 16 + fr;
#pragma unroll
      for (int ks = 0; ks < 2; ++ks)
        b1[nf][ks] = *(const bf16x8*)
            &Bs0[8192 + row * 64 + (((ks * 4 + quad) ^ (fr & 7)) << 3)];
    }
    if (t + 2 < NT) { STAGE_B64(0, t + 2); STAGE_A64(0, t + 2); }
    asm volatile("s_barrier" ::: "memory");
    asm volatile("s_waitcnt lgkmcnt(0)" ::: "memory");
    __builtin_amdgcn_s_setprio(1);
    MFMA16(0, 1, af, b1)
    __builtin_amdgcn_s_setprio(0);
    asm volatile("s_barrier" ::: "memory");

    // ---------- phase 2: read A-h1; stage B1(t+2); MFMA (1,1) ----------
#pragma unroll
    for (int mf = 0; mf < 4; ++mf) {
      const int row = wm * 64 + mf * 16 + fr;
#pragma unroll
      for (int ks = 0; ks < 2; ++ks)
        af[mf][ks] = *(const bf16x8*)
            &As0[8192 + row * 64 + (((ks * 4 + quad) ^ (fr & 7)) << 3)];
    }
    if (t + 2 < NT) STAGE_B64(1, t + 2);
    asm volatile("s_barrier" ::: "memory");
    asm volatile("s_waitcnt lgkmcnt(0)" ::: "memory");
    __builtin_amdgcn_s_setprio(1);
    MFMA16(1, 1, af, b1)
    __builtin_amdgcn_s_setprio(0);
    asm volatile("s_barrier" ::: "memory");

    // ---------- phase 3: stage A1(t+2); counted vmcnt; MFMA (1,0) ----------
    if (t + 2 < NT) STAGE_A64(1, t + 2);
    if (t < NT - 2) asm volatile("s_waitcnt vmcnt(8)" ::: "memory");
    else            asm volatile("s_waitcnt vmcnt(0)" ::: "memory");
    asm volatile("s_barrier" ::: "memory");
    __builtin_amdgcn_s_setprio(1);
    MFMA16(1, 0, af, b0)
    __builtin_amdgcn_s_setprio(0);
    asm volatile("s_barrier" ::: "memory");
  }

  // ---- epilogue (C/D: row = quad*4+reg rel. M-frag, col = fr rel. N-frag) ----
  const float gscale = (rope_mode == 1) ? 0.08838834764831845f : 1.0f;
  float freqv[2] = {0.f, 0.f};
  if (rope_mode) {
#pragma unroll
    for (int nf = 0; nf < 2; ++nf)
      freqv[nf] = exp2f((float)((wn & 1) * 32 + nf * 16 + fr) *
                        -0.20762050593046012f);
  }
#pragma unroll
  for (int pM = 0; pM < 2; ++pM)
#pragma unroll
    for (int mf = 0; mf < 4; ++mf)
#pragma unroll
      for (int r = 0; r < 4; ++r) {
        const int grow = m0 + pM * 128 + wm * 64 + mf * 16 + quad * 4 + r;
        float fct[2] = {1.f, 1.f};
        if (rope_mode) {
          const int tt = grow & (T_ - 1);
#pragma unroll
          for (int nf = 0; nf < 2; ++nf) {
            float sn, cs;
            sincosf((float)tt * freqv[nf], &sn, &cs);
            fct[nf] = (cs + sn) * gscale;
          }
        }
#pragma unroll
        for (int pN = 0; pN < 2; ++pN)
#pragma unroll
          for (int nf = 0; nf < 2; ++nf) {
            const int col = n0 + pN * 128 + wn * 32 + nf * 16 + fr;
            float v = acc[pM][pN][mf][nf][r] * fct[nf];
            if constexpr (sizeof(OutT) == 4)
              C[(size_t)grow * N + col] = v;
            else
              C[(size_t)grow * N + col] = __float2bfloat16(v);
          }
      }
}

// ---------------------------------------------------------------------------
// Flash attention (causal). Best-known config (R7/R8/R13: 189-205 us,
// run-to-run variance ~+-8%): grid (8,64) two-pass balanced (qt=bx then
// 15-bx, 17 K-tile units/block); R2 dataflow (V staged into shared Ks after
// QK; DMA lands during softmax, which is VALU-only); halved per-wave Ps
// (48 KiB LDS); launch_bounds(256,2) (VGPR 128, no spill -- NEVER cap below
// 128: R4's (256,3) forced VGPR 84 and spilled accumulators, 2x regression).
// Grid notes: (12,64) 3-blocks/CU REGRESSED (R12); 1024 single-tile blocks
// REGRESSED (R5); K/V split-buffer deep pipeline REGRESSED (R6); T13
// defer-max dual-path REGRESSED via scratch demotion (R3).
// ---------------------------------------------------------------------------
__global__ __launch_bounds__(256, 2) void flash_attn(
    const __hip_bfloat16* __restrict__ Q,
    const __hip_bfloat16* __restrict__ K,
    const __hip_bfloat16* __restrict__ Vt,
    __hip_bfloat16* __restrict__ O)
{
  __shared__ __align__(16) __hip_bfloat16 Ks[128 * 128];
  __shared__ __align__(16) __hip_bfloat16 Ps[4][32 * 64];
  const int tid = threadIdx.x, lane = tid & 63, wid = tid >> 6;
  const int bx = blockIdx.x, bh = blockIdx.y;
  const int b = bh >> 5, h = bh & 31;
  const int fr = lane & 15;
  const int quad = lane >> 4;
  const __hip_bfloat16* Kbase = K + (size_t)(b * T_) * C_ + h * D_;
  const __hip_bfloat16* Vbase = Vt + (size_t)bh * D_ * T_;

  const int strow = wid * 32 + quad;  // +4 per j

  for (int pass = 0; pass < 2; ++pass) {
    const int qt = pass ? (15 - bx) : bx;
    const int q0 = qt * 128;
    const __hip_bfloat16* Qbase = Q + (size_t)(b * T_ + q0) * C_ + h * D_;

    // ---- stage Q tile (source-swizzled), pull fragments ----
#pragma unroll
    for (int j = 0; j < 8; ++j) {
      const int swz = quad + (j & 1) * 4;
      gload_lds16(Qbase + (size_t)(strow + j * 4) * C_ + ((fr ^ swz) * 8),
                  &Ks[(wid * 8 + j) * 512]);
    }
    __syncthreads();
    bf16x8 qf[2][4];
#pragma unroll
    for (int mi = 0; mi < 2; ++mi)
#pragma unroll
      for (int ks = 0; ks < 4; ++ks)
        qf[mi][ks] = *(const bf16x8*)&Ks[(wid * 32 + mi * 16 + fr) * 128 +
                                         (((ks * 4 + quad) ^ (fr & 7)) << 3)];
    __syncthreads();

    float m_i[2][4], l_i[2][4];
#pragma unroll
    for (int mi = 0; mi < 2; ++mi)
#pragma unroll
      for (int r = 0; r < 4; ++r) { m_i[mi][r] = -1e30f; l_i[mi][r] = 0.f; }
    f32x4 oa[2][8] = {};

    for (int kt = 0; kt <= qt; ++kt) {
#pragma unroll
      for (int j = 0; j < 8; ++j) {
        const int swz = quad + (j & 1) * 4;
        gload_lds16(
            Kbase + (size_t)(kt * 128 + strow + j * 4) * C_ + ((fr ^ swz) * 8),
            &Ks[(wid * 8 + j) * 512]);
      }
      __syncthreads();

      f32x4 s[2][8] = {};
#pragma unroll
      for (int ks = 0; ks < 4; ++ks) {
        bf16x8 kf[8];
#pragma unroll
        for (int ni = 0; ni < 8; ++ni)
          kf[ni] = *(const bf16x8*)&Ks[(ni * 16 + fr) * 128 +
                                       (((ks * 4 + quad) ^ (fr & 7)) << 3)];
        __builtin_amdgcn_s_setprio(1);
#pragma unroll
        for (int mi = 0; mi < 2; ++mi)
#pragma unroll
          for (int ni = 0; ni < 8; ++ni)
            s[mi][ni] = __builtin_amdgcn_mfma_f32_16x16x32_bf16(
                qf[mi][ks], kf[ni], s[mi][ni], 0, 0, 0);
        __builtin_amdgcn_s_setprio(0);
      }
      __syncthreads();  // K tile consumed

      // stage Vt tile into the same buffer (async; lands during softmax)
#pragma unroll
      for (int j = 0; j < 8; ++j) {
        const int swz = quad + (j & 1) * 4;
        gload_lds16(
            Vbase + (size_t)(strow + j * 4) * T_ + kt * 128 + ((fr ^ swz) * 8),
            &Ks[(wid * 8 + j) * 512]);
      }

      if (kt == qt) {
#pragma unroll
        for (int mi = 0; mi < 2; ++mi)
#pragma unroll
          for (int ni = 0; ni < 8; ++ni)
#pragma unroll
            for (int r = 0; r < 4; ++r) {
              int rl = wid * 32 + mi * 16 + quad * 4 + r;
              int cl = ni * 16 + fr;
              if (cl > rl) s[mi][ni][r] = -1e30f;
            }
      }

      // ---- softmax (single path, always rescale) ----
#pragma unroll
      for (int mi = 0; mi < 2; ++mi)
#pragma unroll
        for (int r = 0; r < 4; ++r) {
          float mx = -1e30f;
#pragma unroll
          for (int ni = 0; ni < 8; ++ni) mx = fmaxf(mx, s[mi][ni][r]);
          mx = fmaxf(mx, __shfl_xor(mx, 1, 16));
          mx = fmaxf(mx, __shfl_xor(mx, 2, 16));
          mx = fmaxf(mx, __shfl_xor(mx, 4, 16));
          mx = fmaxf(mx, __shfl_xor(mx, 8, 16));
          float mnew = fmaxf(m_i[mi][r], mx);
          float alpha = __expf(m_i[mi][r] - mnew);
          float rs = 0.f;
#pragma unroll
          for (int ni = 0; ni < 8; ++ni) {
            float p = __expf(s[mi][ni][r] - mnew);
            s[mi][ni][r] = p;
            rs += p;
          }
          rs += __shfl_xor(rs, 1, 16);
          rs += __shfl_xor(rs, 2, 16);
          rs += __shfl_xor(rs, 4, 16);
          rs += __shfl_xor(rs, 8, 16);
          m_i[mi][r] = mnew;
          l_i[mi][r] = l_i[mi][r] * alpha + rs;
#pragma unroll
          for (int ni = 0; ni < 8; ++ni) oa[mi][ni][r] *= alpha;
        }

      // ---- P round-trip in two 64-col halves + PV ----
#pragma unroll
      for (int hh = 0; hh < 2; ++hh) {
        // write P half hh (cols hh*64 .. hh*64+63) into per-wave Ps
#pragma unroll
        for (int mi = 0; mi < 2; ++mi)
#pragma unroll
          for (int l = 0; l < 4; ++l) {
            const int sw = (l ^ quad) & 3;
#pragma unroll
            for (int r = 0; r < 4; ++r)
              Ps[wid][(mi * 16 + quad * 4 + r) * 64 + sw * 16 + fr] =
                  __float2bfloat16(s[mi][hh * 4 + l][r]);
          }
        if (hh == 0) __syncthreads();  // Vt landed (vmcnt drained)
        // PV for ks = hh*2, hh*2+1 (wave-ordered LDS: no barrier for hh=1)
#pragma unroll
        for (int kl = 0; kl < 2; ++kl) {
          const int ks = hh * 2 + kl;
          bf16x8 pf[2], vf[8];
#pragma unroll
          for (int mi = 0; mi < 2; ++mi) {
            const int rowl = mi * 16 + fr;
            const int sw = ((kl * 2 + (quad >> 1)) ^ ((fr >> 2) & 3)) & 3;
            pf[mi] = *(const bf16x8*)
                &Ps[wid][rowl * 64 + sw * 16 + (quad & 1) * 8];
          }
#pragma unroll
          for (int ni = 0; ni < 8; ++ni)
            vf[ni] = *(const bf16x8*)&Ks[(ni * 16 + fr) * 128 +
                                         (((ks * 4 + quad) ^ (fr & 7)) << 3)];
          __builtin_amdgcn_s_setprio(1);
#pragma unroll
          for (int mi = 0; mi < 2; ++mi)
#pragma unroll
            for (int ni = 0; ni < 8; ++ni)
              oa[mi][ni] = __builtin_amdgcn_mfma_f32_16x16x32_bf16(
                  pf[mi], vf[ni], oa[mi][ni], 0, 0, 0);
          __builtin_amdgcn_s_setprio(0);
        }
      }
      __syncthreads();  // Vt/Ps consumed
    }

    // ---- epilogue: O / l ----
#pragma unroll
    for (int mi = 0; mi < 2; ++mi)
#pragma unroll
      for (int r = 0; r < 4; ++r) {
        float inv = 1.f / l_i[mi][r];
        int grow = b * T_ + q0 + wid * 32 + mi * 16 + quad * 4 + r;
#pragma unroll
        for (int ni = 0; ni < 8; ++ni)
          O[(size_t)grow * C_ + h * D_ + ni * 16 + fr] =
              __float2bfloat16(oa[mi][ni][r] * inv);
      }
  }
}

// ---------------------------------------------------------------------------
extern "C" void kernel_launch(void* const* d_in, const int* in_sizes, int n_in,
                              void* d_out, int out_size, void* d_ws, size_t ws_size,
                              hipStream_t stream) {
  const float* X  = (const float*)d_in[0];
  const float* Wq = (const float*)d_in[1];
  const float* Wk = (const float*)d_in[2];
  const float* Wv = (const float*)d_in[3];
  const float* Wo = (const float*)d_in[4];
  float* out = (float*)d_out;

  char* ws = (char*)d_ws;
  const size_t SZ = (size_t)4096 * 4096 * 2;  // 32 MiB per bf16 slab
  __hip_bfloat16* Xb  = (__hip_bfloat16*)(ws);
  __hip_bfloat16* Wt  = (__hip_bfloat16*)(ws + SZ);
  __hip_bfloat16* Qb  = (__hip_bfloat16*)(ws + 2 * SZ);
  __hip_bfloat16* Kb  = (__hip_bfloat16*)(ws + 3 * SZ);
  __hip_bfloat16* Vb  = (__hip_bfloat16*)(ws + 4 * SZ);
  __hip_bfloat16* Vtb = Xb;   // Xb dead after QKV GEMMs
  __hip_bfloat16* Ob  = Vb;   // V dead after Vt transpose

  const dim3 blk(256);
  const dim3 gT(64, 64, 1);

  // 128 KiB dynamic LDS for the 256^2 GEMM
  hipFuncSetAttribute(reinterpret_cast<const void*>(&gemm256<__hip_bfloat16>),
                      hipFuncAttributeMaxDynamicSharedMemorySize, 131072);
  hipFuncSetAttribute(reinterpret_cast<const void*>(&gemm256<float>),
                      hipFuncAttributeMaxDynamicSharedMemorySize, 131072);

  // X -> bf16
  cvt_f32_bf16<<<8192, blk, 0, stream>>>(X, (ushort*)Xb);

  // Q = rope(X @ Wq) / sqrt(D) ; K = rope(X @ Wk) ; V = X @ Wv
  transpose_f32_bf16<<<gT, blk, 0, stream>>>(Wq, (ushort*)Wt, 4096, 4096);
  gemm256<__hip_bfloat16><<<dim3(256), dim3(512), 131072, stream>>>(
      Xb, Wt, Qb, 4096, 4096, 4096, 1);
  transpose_f32_bf16<<<gT, blk, 0, stream>>>(Wk, (ushort*)Wt, 4096, 4096);
  gemm256<__hip_bfloat16><<<dim3(256), dim3(512), 131072, stream>>>(
      Xb, Wt, Kb, 4096, 4096, 4096, 2);
  transpose_f32_bf16<<<gT, blk, 0, stream>>>(Wv, (ushort*)Wt, 4096, 4096);
  gemm256<__hip_bfloat16><<<dim3(256), dim3(512), 131072, stream>>>(
      Xb, Wt, Vb, 4096, 4096, 4096, 0);

  // Vt[b,h,d,t] = V[b,t,h*128+d]
  transpose_bf16<<<dim3(2, 32, 64), blk, 0, stream>>>(
      (const ushort*)Vb, (ushort*)Vtb, 4096, 2048,
      /*zi1 h*/ 128, /*zi2 b*/ 8388608, /*zo1 h*/ 262144, /*zo2 b*/ 8388608);

  // attention (balanced two-pass causal schedule)
  flash_attn<<<dim3(8, 64), blk, 0, stream>>>(Qb, Kb, Vtb, Ob);

  // out = O @ Wo  (fp32 output)
  transpose_f32_bf16<<<gT, blk, 0, stream>>>(Wo, (ushort*)Wt, 4096, 4096);
  gemm256<float><<<dim3(256), dim3(512), 131072, stream>>>(
      Ob, Wt, out, 4096, 4096, 4096, 0);
}

// Round 17
// 1012.524 us; speedup vs baseline: 1.0107x; 1.0010x over previous
//
#include <hip/hip_runtime.h>
#include <hip/hip_bf16.h>

#define B_ 2
#define T_ 2048
#define C_ 4096
#define H_ 32
#define D_ 128

typedef __bf16 bf16x8 __attribute__((ext_vector_type(8)));
typedef float f32x4 __attribute__((ext_vector_type(4)));

__device__ __forceinline__ void gload_lds16(const void* g, void* l) {
  __builtin_amdgcn_global_load_lds(
      (const __attribute__((address_space(1))) void*)g,
      (__attribute__((address_space(3))) void*)l, 16, 0, 0);
}

__device__ __forceinline__ ushort f2bf(float f) {
  union { float f; uint u; } x; x.f = f;
  uint r = x.u + 0x7FFFu + ((x.u >> 16) & 1u);   // round-to-nearest-even
  return (ushort)(r >> 16);
}

// ---------------------------------------------------------------------------
// fp32 -> bf16 elementwise convert (8 elements/thread)
// ---------------------------------------------------------------------------
__global__ __launch_bounds__(256) void cvt_f32_bf16(
    const float* __restrict__ in, ushort* __restrict__ out)
{
  long i = ((long)blockIdx.x * 256 + threadIdx.x) * 8;
  float4 a = *(const float4*)&in[i];
  float4 b = *(const float4*)&in[i + 4];
  union { ushort u[8]; uint4 v; } g;
  g.u[0] = f2bf(a.x); g.u[1] = f2bf(a.y); g.u[2] = f2bf(a.z); g.u[3] = f2bf(a.w);
  g.u[4] = f2bf(b.x); g.u[5] = f2bf(b.y); g.u[6] = f2bf(b.z); g.u[7] = f2bf(b.w);
  *(uint4*)&out[i] = g.v;
}

// ---------------------------------------------------------------------------
// Fused transpose + fp32->bf16 convert: out[c][r] = bf16(in[r][c]).
// ---------------------------------------------------------------------------
__global__ __launch_bounds__(256) void transpose_f32_bf16(
    const float* __restrict__ in, ushort* __restrict__ out, int ldi, int ldo)
{
  __shared__ __align__(16) ushort tile[64][72];
  const float* ip = in + (long)blockIdx.y * 64 * ldi + (long)blockIdx.x * 64;
  ushort* op = out + (long)blockIdx.x * 64 * ldo + (long)blockIdx.y * 64;
  const int t = threadIdx.x;
  const int row = t >> 2, c0 = (t & 3) * 16;
#pragma unroll
  for (int v = 0; v < 4; ++v) {
    float4 f = *(const float4*)&ip[(long)row * ldi + c0 + v * 4];
    ushort4 w;
    w.x = f2bf(f.x); w.y = f2bf(f.y); w.z = f2bf(f.z); w.w = f2bf(f.w);
    *(ushort4*)&tile[row][c0 + v * 4] = w;
  }
  __syncthreads();
#pragma unroll
  for (int i = 0; i < 2; ++i) {
    int t2 = i * 256 + t;
    int orow = t2 >> 3, ch = t2 & 7;
    union { ushort u[8]; uint4 v; } g;
#pragma unroll
    for (int e = 0; e < 8; ++e) g.u[e] = tile[ch * 8 + e][orow];
    *(uint4*)&op[(long)orow * ldo + ch * 8] = g.v;
  }
}

// ---------------------------------------------------------------------------
// bf16 transpose with z-striding (for V -> Vt[b,h,d,t]).
// ---------------------------------------------------------------------------
__global__ __launch_bounds__(256) void transpose_bf16(
    const ushort* __restrict__ in, ushort* __restrict__ out,
    int ldi, int ldo, long zi1, long zi2, long zo1, long zo2)
{
  __shared__ __align__(16) ushort tile[64][72];
  const int z = blockIdx.z;
  const long z1 = z & 31, z2 = z >> 5;
  const ushort* ip = in + z1 * zi1 + z2 * zi2 +
                     (long)blockIdx.y * 64 * ldi + (long)blockIdx.x * 64;
  ushort* op = out + z1 * zo1 + z2 * zo2 +
               (long)blockIdx.x * 64 * ldo + (long)blockIdx.y * 64;
  const int t = threadIdx.x;
#pragma unroll
  for (int i = 0; i < 2; ++i) {
    int t2 = i * 256 + t;
    int row = t2 >> 3, ch = t2 & 7;
    *(uint4*)&tile[row][ch * 8] = *(const uint4*)&ip[(long)row * ldi + ch * 8];
  }
  __syncthreads();
#pragma unroll
  for (int i = 0; i < 2; ++i) {
    int t2 = i * 256 + t;
    int orow = t2 >> 3, ch = t2 & 7;
    union { ushort u[8]; uint4 v; } g;
#pragma unroll
    for (int e = 0; e < 8; ++e) g.u[e] = tile[ch * 8 + e][orow];
    *(uint4*)&op[(long)orow * ldo + ch * 8] = g.v;
  }
}

// ===========================================================================
// GEMM 256x256 tile, BK=64, 128 KiB LDS, 8 waves, 4-phase Gray schedule,
// deep prefetch (t+2), B-frags persistent in regs, counted vmcnt(8),
// XOR-chunk LDS swizzle via pre-swizzled global source, XCD-bijective
// block swizzle. Best-known single-GEMM config (~176 us, grid 256).
// Session notes: sched_barrier(0) removal = null; BK=32 = regressed
// (barrier-rate up, no overlap gain at grid=256=1 block/CU); fused-QKV
// (grid 768, 2 blocks/CU) = faster in-dispatch (428 vs 528 us, MfmaUtil 43%)
// but consistently slower end-to-end (~+100 us systemic, never localized).
// ===========================================================================
#define STAGE_A64(h, tt) do {                                                  \
    __hip_bfloat16* dst_ = AS + ((((tt) & 1) * 2 + (h)) * 8192) + w * 512;     \
    const __hip_bfloat16* src_ = Asrc + (size_t)((h) * 128) * K + (size_t)(tt) * 64; \
    gload_lds16(src_, dst_);                                                   \
    gload_lds16(src_ + (size_t)64 * K, dst_ + 4096);                           \
  } while (0)

#define STAGE_B64(h, tt) do {                                                  \
    __hip_bfloat16* dst_ = BS + ((((tt) & 1) * 2 + (h)) * 8192) + w * 512;     \
    const __hip_bfloat16* src_ = Bsrc + (size_t)((h) * 128) * K + (size_t)(tt) * 64; \
    gload_lds16(src_, dst_);                                                   \
    gload_lds16(src_ + (size_t)64 * K, dst_ + 4096);                           \
  } while (0)

#define MFMA16(pM, pN, AF, BF)                                                 \
  _Pragma("unroll")                                                            \
  for (int mf = 0; mf < 4; ++mf)                                               \
    _Pragma("unroll")                                                          \
    for (int nf = 0; nf < 2; ++nf)                                             \
      _Pragma("unroll")                                                        \
      for (int ks = 0; ks < 2; ++ks)                                           \
        acc[pM][pN][mf][nf] = __builtin_amdgcn_mfma_f32_16x16x32_bf16(         \
            AF[mf][ks], BF[nf][ks], acc[pM][pN][mf][nf], 0, 0, 0);

template <typename OutT>
__global__ __launch_bounds__(512, 2) void gemm256(
    const __hip_bfloat16* __restrict__ A,
    const __hip_bfloat16* __restrict__ Bt,
    OutT* __restrict__ C,
    int M, int N, int K, int rope_mode)
{
  extern __shared__ __hip_bfloat16 smem[];
  __hip_bfloat16* AS = smem;            // 2 buf x 2 half x 8192 elem (64 KiB)
  __hip_bfloat16* BS = smem + 32768;    // same (64 KiB)

  const int tid = threadIdx.x, lane = tid & 63, w = tid >> 6;
  const int wm = w >> 2, wn = w & 3;          // 2M x 4N wave grid
  const int fr = lane & 15, quad = lane >> 4;

  // XCD-bijective block swizzle (nwg=256, 256%8==0)
  const int bid = blockIdx.x;
  const int s = (bid & 7) * 32 + (bid >> 3);
  const int m0 = (s >> 4) * 256, n0 = (s & 15) * 256;

  // staging source: thread covers row (tid>>3), 16B chunk pre-swizzled
  const int srow = tid >> 3;                       // 0..63
  const int schunk = ((tid & 7) ^ (srow & 7)) * 8;
  const __hip_bfloat16* Asrc = A + (size_t)(m0 + srow) * K + schunk;
  const __hip_bfloat16* Bsrc = Bt + (size_t)(n0 + srow) * K + schunk;

  f32x4 acc[2][2][4][2] = {};

  // ---- prologue: tiles 0 and 1 fully staged ----
  STAGE_A64(0, 0); STAGE_B64(0, 0); STAGE_A64(1, 0); STAGE_B64(1, 0);
  STAGE_A64(0, 1); STAGE_B64(0, 1); STAGE_A64(1, 1); STAGE_B64(1, 1);
  asm volatile("s_waitcnt vmcnt(8)" ::: "memory");   // tile0 landed
  asm volatile("s_barrier" ::: "memory");

  const int NT = K >> 6;
  for (int t = 0; t < NT; ++t) {
    const __hip_bfloat16* As0 = AS + (t & 1) * 16384;
    const __hip_bfloat16* Bs0 = BS + (t & 1) * 16384;
    bf16x8 af[4][2], b0[2][2], b1[2][2];

    // ---------- phase 0: read A-h0 + B-h0; MFMA (0,0) ----------
#pragma unroll
    for (int mf = 0; mf < 4; ++mf) {
      const int row = wm * 64 + mf * 16 + fr;
#pragma unroll
      for (int ks = 0; ks < 2; ++ks)
        af[mf][ks] = *(const bf16x8*)
            &As0[row * 64 + (((ks * 4 + quad) ^ (fr & 7)) << 3)];
    }
#pragma unroll
    for (int nf = 0; nf < 2; ++nf) {
      const int row = wn * 32 + nf * 16 + fr;
#pragma unroll
      for (int ks = 0; ks < 2; ++ks)
        b0[nf][ks] = *(const bf16x8*)
            &Bs0[row * 64 + (((ks * 4 + quad) ^ (fr & 7)) << 3)];
    }
    asm volatile("s_barrier" ::: "memory");
    asm volatile("s_waitcnt lgkmcnt(0)" ::: "memory");
    __builtin_amdgcn_s_setprio(1);
    MFMA16(0, 0, af, b0)
    __builtin_amdgcn_s_setprio(0);
    asm volatile("s_barrier" ::: "memory");

    // ---------- phase 1: read B-h1; stage B0,A0 (t+2); MFMA (0,1) ----------
#pragma unroll
    for (int nf = 0; nf < 2; ++nf) {
      const int row = wn * 32 + nf * 16 + fr;
#pragma unroll
      for (int ks = 0; ks < 2; ++ks)
        b1[nf][ks] = *(const bf16x8*)
            &Bs0[8192 + row * 64 + (((ks * 4 + quad) ^ (fr & 7)) << 3)];
    }
    if (t + 2 < NT) { STAGE_B64(0, t + 2); STAGE_A64(0, t + 2); }
    asm volatile("s_barrier" ::: "memory");
    asm volatile("s_waitcnt lgkmcnt(0)" ::: "memory");
    __builtin_amdgcn_s_setprio(1);
    MFMA16(0, 1, af, b1)
    __builtin_amdgcn_s_setprio(0);
    asm volatile("s_barrier" ::: "memory");

    // ---------- phase 2: read A-h1; stage B1(t+2); MFMA (1,1) ----------
#pragma unroll
    for (int mf = 0; mf < 4; ++mf) {
      const int row = wm * 64 + mf * 16 + fr;
#pragma unroll
      for (int ks = 0; ks < 2; ++ks)
        af[mf][ks] = *(const bf16x8*)
            &As0[8192 + row * 64 + (((ks * 4 + quad) ^ (fr & 7)) << 3)];
    }
    if (t + 2 < NT) STAGE_B64(1, t + 2);
    asm volatile("s_barrier" ::: "memory");
    asm volatile("s_waitcnt lgkmcnt(0)" ::: "memory");
    __builtin_amdgcn_s_setprio(1);
    MFMA16(1, 1, af, b1)
    __builtin_amdgcn_s_setprio(0);
    asm volatile("s_barrier" ::: "memory");

    // ---------- phase 3: stage A1(t+2); counted vmcnt; MFMA (1,0) ----------
    if (t + 2 < NT) STAGE_A64(1, t + 2);
    if (t < NT - 2) asm volatile("s_waitcnt vmcnt(8)" ::: "memory");
    else            asm volatile("s_waitcnt vmcnt(0)" ::: "memory");
    asm volatile("s_barrier" ::: "memory");
    __builtin_amdgcn_s_setprio(1);
    MFMA16(1, 0, af, b0)
    __builtin_amdgcn_s_setprio(0);
    asm volatile("s_barrier" ::: "memory");
  }

  // ---- epilogue (C/D: row = quad*4+reg rel. M-frag, col = fr rel. N-frag) ----
  const float gscale = (rope_mode == 1) ? 0.08838834764831845f : 1.0f;
  float freqv[2] = {0.f, 0.f};
  if (rope_mode) {
#pragma unroll
    for (int nf = 0; nf < 2; ++nf)
      freqv[nf] = exp2f((float)((wn & 1) * 32 + nf * 16 + fr) *
                        -0.20762050593046012f);
  }
#pragma unroll
  for (int pM = 0; pM < 2; ++pM)
#pragma unroll
    for (int mf = 0; mf < 4; ++mf)
#pragma unroll
      for (int r = 0; r < 4; ++r) {
        const int grow = m0 + pM * 128 + wm * 64 + mf * 16 + quad * 4 + r;
        float fct[2] = {1.f, 1.f};
        if (rope_mode) {
          const int tt = grow & (T_ - 1);
#pragma unroll
          for (int nf = 0; nf < 2; ++nf) {
            float sn, cs;
            sincosf((float)tt * freqv[nf], &sn, &cs);
            fct[nf] = (cs + sn) * gscale;
          }
        }
#pragma unroll
        for (int pN = 0; pN < 2; ++pN)
#pragma unroll
          for (int nf = 0; nf < 2; ++nf) {
            const int col = n0 + pN * 128 + wn * 32 + nf * 16 + fr;
            float v = acc[pM][pN][mf][nf][r] * fct[nf];
            if constexpr (sizeof(OutT) == 4)
              C[(size_t)grow * N + col] = v;
            else
              C[(size_t)grow * N + col] = __float2bfloat16(v);
          }
      }
}

// ---------------------------------------------------------------------------
// Flash attention (causal). Best-known config (189-205 us, run-to-run
// variance ~+-8%): grid (8,64) two-pass balanced (qt=bx then 15-bx, 17
// K-tile units/block); R2 dataflow (V staged into shared Ks after QK; DMA
// lands during softmax, which is VALU-only); halved per-wave Ps (48 KiB
// LDS); launch_bounds(256,2) (VGPR 128, no spill -- NEVER cap below 128:
// (256,3) forced VGPR 84 and spilled accumulators, 2x regression).
// Grid notes: (12,64) 3-blocks/CU REGRESSED (3 KV streams/CU thrash L2);
// 1024 single-tile blocks REGRESSED (workload skew); K/V split-buffer deep
// pipeline REGRESSED (K-prefetch DMA steals LDS BW during PV); T13
// defer-max dual-path REGRESSED via scratch demotion.
// ---------------------------------------------------------------------------
__global__ __launch_bounds__(256, 2) void flash_attn(
    const __hip_bfloat16* __restrict__ Q,
    const __hip_bfloat16* __restrict__ K,
    const __hip_bfloat16* __restrict__ Vt,
    __hip_bfloat16* __restrict__ O)
{
  __shared__ __align__(16) __hip_bfloat16 Ks[128 * 128];
  __shared__ __align__(16) __hip_bfloat16 Ps[4][32 * 64];
  const int tid = threadIdx.x, lane = tid & 63, wid = tid >> 6;
  const int bx = blockIdx.x, bh = blockIdx.y;
  const int b = bh >> 5, h = bh & 31;
  const int fr = lane & 15;
  const int quad = lane >> 4;
  const __hip_bfloat16* Kbase = K + (size_t)(b * T_) * C_ + h * D_;
  const __hip_bfloat16* Vbase = Vt + (size_t)bh * D_ * T_;

  const int strow = wid * 32 + quad;  // +4 per j

  for (int pass = 0; pass < 2; ++pass) {
    const int qt = pass ? (15 - bx) : bx;
    const int q0 = qt * 128;
    const __hip_bfloat16* Qbase = Q + (size_t)(b * T_ + q0) * C_ + h * D_;

    // ---- stage Q tile (source-swizzled), pull fragments ----
#pragma unroll
    for (int j = 0; j < 8; ++j) {
      const int swz = quad + (j & 1) * 4;
      gload_lds16(Qbase + (size_t)(strow + j * 4) * C_ + ((fr ^ swz) * 8),
                  &Ks[(wid * 8 + j) * 512]);
    }
    __syncthreads();
    bf16x8 qf[2][4];
#pragma unroll
    for (int mi = 0; mi < 2; ++mi)
#pragma unroll
      for (int ks = 0; ks < 4; ++ks)
        qf[mi][ks] = *(const bf16x8*)&Ks[(wid * 32 + mi * 16 + fr) * 128 +
                                         (((ks * 4 + quad) ^ (fr & 7)) << 3)];
    __syncthreads();

    float m_i[2][4], l_i[2][4];
#pragma unroll
    for (int mi = 0; mi < 2; ++mi)
#pragma unroll
      for (int r = 0; r < 4; ++r) { m_i[mi][r] = -1e30f; l_i[mi][r] = 0.f; }
    f32x4 oa[2][8] = {};

    for (int kt = 0; kt <= qt; ++kt) {
#pragma unroll
      for (int j = 0; j < 8; ++j) {
        const int swz = quad + (j & 1) * 4;
        gload_lds16(
            Kbase + (size_t)(kt * 128 + strow + j * 4) * C_ + ((fr ^ swz) * 8),
            &Ks[(wid * 8 + j) * 512]);
      }
      __syncthreads();

      f32x4 s[2][8] = {};
#pragma unroll
      for (int ks = 0; ks < 4; ++ks) {
        bf16x8 kf[8];
#pragma unroll
        for (int ni = 0; ni < 8; ++ni)
          kf[ni] = *(const bf16x8*)&Ks[(ni * 16 + fr) * 128 +
                                       (((ks * 4 + quad) ^ (fr & 7)) << 3)];
        __builtin_amdgcn_s_setprio(1);
#pragma unroll
        for (int mi = 0; mi < 2; ++mi)
#pragma unroll
          for (int ni = 0; ni < 8; ++ni)
            s[mi][ni] = __builtin_amdgcn_mfma_f32_16x16x32_bf16(
                qf[mi][ks], kf[ni], s[mi][ni], 0, 0, 0);
        __builtin_amdgcn_s_setprio(0);
      }
      __syncthreads();  // K tile consumed

      // stage Vt tile into the same buffer (async; lands during softmax)
#pragma unroll
      for (int j = 0; j < 8; ++j) {
        const int swz = quad + (j & 1) * 4;
        gload_lds16(
            Vbase + (size_t)(strow + j * 4) * T_ + kt * 128 + ((fr ^ swz) * 8),
            &Ks[(wid * 8 + j) * 512]);
      }

      if (kt == qt) {
#pragma unroll
        for (int mi = 0; mi < 2; ++mi)
#pragma unroll
          for (int ni = 0; ni < 8; ++ni)
#pragma unroll
            for (int r = 0; r < 4; ++r) {
              int rl = wid * 32 + mi * 16 + quad * 4 + r;
              int cl = ni * 16 + fr;
              if (cl > rl) s[mi][ni][r] = -1e30f;
            }
      }

      // ---- softmax (single path, always rescale) ----
#pragma unroll
      for (int mi = 0; mi < 2; ++mi)
#pragma unroll
        for (int r = 0; r < 4; ++r) {
          float mx = -1e30f;
#pragma unroll
          for (int ni = 0; ni < 8; ++ni) mx = fmaxf(mx, s[mi][ni][r]);
          mx = fmaxf(mx, __shfl_xor(mx, 1, 16));
          mx = fmaxf(mx, __shfl_xor(mx, 2, 16));
          mx = fmaxf(mx, __shfl_xor(mx, 4, 16));
          mx = fmaxf(mx, __shfl_xor(mx, 8, 16));
          float mnew = fmaxf(m_i[mi][r], mx);
          float alpha = __expf(m_i[mi][r] - mnew);
          float rs = 0.f;
#pragma unroll
          for (int ni = 0; ni < 8; ++ni) {
            float p = __expf(s[mi][ni][r] - mnew);
            s[mi][ni][r] = p;
            rs += p;
          }
          rs += __shfl_xor(rs, 1, 16);
          rs += __shfl_xor(rs, 2, 16);
          rs += __shfl_xor(rs, 4, 16);
          rs += __shfl_xor(rs, 8, 16);
          m_i[mi][r] = mnew;
          l_i[mi][r] = l_i[mi][r] * alpha + rs;
#pragma unroll
          for (int ni = 0; ni < 8; ++ni) oa[mi][ni][r] *= alpha;
        }

      // ---- P round-trip in two 64-col halves + PV ----
#pragma unroll
      for (int hh = 0; hh < 2; ++hh) {
        // write P half hh (cols hh*64 .. hh*64+63) into per-wave Ps
#pragma unroll
        for (int mi = 0; mi < 2; ++mi)
#pragma unroll
          for (int l = 0; l < 4; ++l) {
            const int sw = (l ^ quad) & 3;
#pragma unroll
            for (int r = 0; r < 4; ++r)
              Ps[wid][(mi * 16 + quad * 4 + r) * 64 + sw * 16 + fr] =
                  __float2bfloat16(s[mi][hh * 4 + l][r]);
          }
        if (hh == 0) __syncthreads();  // Vt landed (vmcnt drained)
        // PV for ks = hh*2, hh*2+1 (wave-ordered LDS: no barrier for hh=1)
#pragma unroll
        for (int kl = 0; kl < 2; ++kl) {
          const int ks = hh * 2 + kl;
          bf16x8 pf[2], vf[8];
#pragma unroll
          for (int mi = 0; mi < 2; ++mi) {
            const int rowl = mi * 16 + fr;
            const int sw = ((kl * 2 + (quad >> 1)) ^ ((fr >> 2) & 3)) & 3;
            pf[mi] = *(const bf16x8*)
                &Ps[wid][rowl * 64 + sw * 16 + (quad & 1) * 8];
          }
#pragma unroll
          for (int ni = 0; ni < 8; ++ni)
            vf[ni] = *(const bf16x8*)&Ks[(ni * 16 + fr) * 128 +
                                         (((ks * 4 + quad) ^ (fr & 7)) << 3)];
          __builtin_amdgcn_s_setprio(1);
#pragma unroll
          for (int mi = 0; mi < 2; ++mi)
#pragma unroll
            for (int ni = 0; ni < 8; ++ni)
              oa[mi][ni] = __builtin_amdgcn_mfma_f32_16x16x32_bf16(
                  pf[mi], vf[ni], oa[mi][ni], 0, 0, 0);
          __builtin_amdgcn_s_setprio(0);
        }
      }
      __syncthreads();  // Vt/Ps consumed
    }

    // ---- epilogue: O / l ----
#pragma unroll
    for (int mi = 0; mi < 2; ++mi)
#pragma unroll
      for (int r = 0; r < 4; ++r) {
        float inv = 1.f / l_i[mi][r];
        int grow = b * T_ + q0 + wid * 32 + mi * 16 + quad * 4 + r;
#pragma unroll
        for (int ni = 0; ni < 8; ++ni)
          O[(size_t)grow * C_ + h * D_ + ni * 16 + fr] =
              __float2bfloat16(oa[mi][ni][r] * inv);
      }
  }
}

// ---------------------------------------------------------------------------
extern "C" void kernel_launch(void* const* d_in, const int* in_sizes, int n_in,
                              void* d_out, int out_size, void* d_ws, size_t ws_size,
                              hipStream_t stream) {
  const float* X  = (const float*)d_in[0];
  const float* Wq = (const float*)d_in[1];
  const float* Wk = (const float*)d_in[2];
  const float* Wv = (const float*)d_in[3];
  const float* Wo = (const float*)d_in[4];
  float* out = (float*)d_out;

  char* ws = (char*)d_ws;
  const size_t SZ = (size_t)4096 * 4096 * 2;  // 32 MiB per bf16 slab
  __hip_bfloat16* Xb  = (__hip_bfloat16*)(ws);
  __hip_bfloat16* Wt  = (__hip_bfloat16*)(ws + SZ);
  __hip_bfloat16* Qb  = (__hip_bfloat16*)(ws + 2 * SZ);
  __hip_bfloat16* Kb  = (__hip_bfloat16*)(ws + 3 * SZ);
  __hip_bfloat16* Vb  = (__hip_bfloat16*)(ws + 4 * SZ);
  __hip_bfloat16* Vtb = Xb;   // Xb dead after QKV GEMMs
  __hip_bfloat16* Ob  = Vb;   // V dead after Vt transpose

  const dim3 blk(256);
  const dim3 gT(64, 64, 1);

  // 128 KiB dynamic LDS for the 256^2 GEMM
  hipFuncSetAttribute(reinterpret_cast<const void*>(&gemm256<__hip_bfloat16>),
                      hipFuncAttributeMaxDynamicSharedMemorySize, 131072);
  hipFuncSetAttribute(reinterpret_cast<const void*>(&gemm256<float>),
                      hipFuncAttributeMaxDynamicSharedMemorySize, 131072);

  // X -> bf16
  cvt_f32_bf16<<<8192, blk, 0, stream>>>(X, (ushort*)Xb);

  // Q = rope(X @ Wq) / sqrt(D) ; K = rope(X @ Wk) ; V = X @ Wv
  transpose_f32_bf16<<<gT, blk, 0, stream>>>(Wq, (ushort*)Wt, 4096, 4096);
  gemm256<__hip_bfloat16><<<dim3(256), dim3(512), 131072, stream>>>(
      Xb, Wt, Qb, 4096, 4096, 4096, 1);
  transpose_f32_bf16<<<gT, blk, 0, stream>>>(Wk, (ushort*)Wt, 4096, 4096);
  gemm256<__hip_bfloat16><<<dim3(256), dim3(512), 131072, stream>>>(
      Xb, Wt, Kb, 4096, 4096, 4096, 2);
  transpose_f32_bf16<<<gT, blk, 0, stream>>>(Wv, (ushort*)Wt, 4096, 4096);
  gemm256<__hip_bfloat16><<<dim3(256), dim3(512), 131072, stream>>>(
      Xb, Wt, Vb, 4096, 4096, 4096, 0);

  // Vt[b,h,d,t] = V[b,t,h*128+d]
  transpose_bf16<<<dim3(2, 32, 64), blk, 0, stream>>>(
      (const ushort*)Vb, (ushort*)Vtb, 4096, 2048,
      /*zi1 h*/ 128, /*zi2 b*/ 8388608, /*zo1 h*/ 262144, /*zo2 b*/ 8388608);

  // attention (balanced two-pass causal schedule)
  flash_attn<<<dim3(8, 64), blk, 0, stream>>>(Qb, Kb, Vtb, Ob);

  // out = O @ Wo  (fp32 output)
  transpose_f32_bf16<<<gT, blk, 0, stream>>>(Wo, (ushort*)Wt, 4096, 4096);
  gemm256<float><<<dim3(256), dim3(512), 131072, stream>>>(
      Ob, Wt, out, 4096, 4096, 4096, 0);
}